// Round 8
// baseline (227.093 us; speedup 1.0000x reference)
//
#include <hip/hip_runtime.h>
#include <hip/hip_bf16.h>

#define N_NODES 100000
#define N_EDGES 1600000
#define NB_C 391                    // coarse buckets (dst >> 8)
#define NB_F 3125                   // fine buckets (dst >> 5) = gather blocks; 3125*32 = 100000 exactly
#define NBLK_S 391                  // sort chunks: ceil(1.6M / 4096)
#define CHUNK_E 4096                // one int4 (4 edges) per thread at 1024 threads
#define CAPC 4608                   // coarse arena capacity (mean 4092 + 8 sigma)
#define QCAP 768                    // fine LDS queue cap (mean 512, sd ~23; 768 = +11 sigma)
#define GCSTRIDE 32                 // one counter per 128B line
#define FIXSCALE 1048576.0f         // 2^20 fixed-point scale for LDS int accumulation
#define FIXINV   (1.0f / 1048576.0f)

// hpre/hpre2 packing: dword d of a row = bf16 pair (col d, col d+32).
// Gather: 16 lanes/record, lane loads uint2 (dwords 2m,2m+1, m rotated per stream);
// ds_adds parity-ordered so every atomic wave-instruction is exactly 2 lanes/bank.

typedef short v8s __attribute__((ext_vector_type(8)));
typedef float v4f __attribute__((ext_vector_type(4)));

static __device__ __forceinline__ unsigned pack_bf2(float a, float b) {
    __hip_bfloat162 p = __float22bfloat162_rn(make_float2(a, b));
    return *reinterpret_cast<unsigned*>(&p);
}
static __device__ __forceinline__ float2 bf2_to_f2(unsigned u) {
    __hip_bfloat162 p = *reinterpret_cast<__hip_bfloat162*>(&u);
    return __bfloat1622float2(p);
}

// ---------- K1 (1024 thr): blocks [0,NBLK_S) = coarse bucket scatter; rest = layer-1 GEMM ----------
__global__ __launch_bounds__(1024) void k1_sort_gemm(const int* __restrict__ src,
                                                     const int* __restrict__ dst,
                                                     const float* __restrict__ wgt,
                                                     const float* __restrict__ x,
                                                     const float* __restrict__ W1,
                                                     int* __restrict__ gcount,
                                                     int2* __restrict__ arena,
                                                     unsigned* __restrict__ hpre) {
    __shared__ __align__(16) int smem[13976];   // 55.9 KB union (sort view / gemm view)
    const int b = blockIdx.x;
    const int t = threadIdx.x;

    if (b >= NBLK_S) {
        // ---- layer-1 GEMM tile: hpre[64 nodes][32 dwords] = x_tile @ W1 (packed d,d+32) ----
        unsigned* xs = (unsigned*)smem;              // [64][68]
        unsigned* ws = (unsigned*)smem + 64 * 68;    // [64][68]
        const int tile = b - NBLK_S;
        const int row0 = tile * 64;
        {   // stage W1: fp32 [128][64] -> ws[col] bf16 at short index k (transpose)
            const float2* g2 = (const float2*)W1;
            for (int i = t; i < 64 * 128 / 2; i += 1024) {
                const float2 v = g2[i];
                const int k = (2 * i) >> 6;
                const int c = (2 * i) & 63;
                ((short*)&ws[c * 68])[k]       = (short)(pack_bf2(v.x, 0.f) & 0xFFFF);
                ((short*)&ws[(c + 1) * 68])[k] = (short)(pack_bf2(v.y, 0.f) & 0xFFFF);
            }
        }
        {   // stage x tile: fp32 -> bf16 packed
            const float4* g = (const float4*)x;
            for (int i = t; i < 64 * 32; i += 1024) {
                const int r = i >> 5, cu = i & 31;
                const int row = row0 + r;
                uint2 v = make_uint2(0u, 0u);
                if (row < N_NODES) {
                    float4 f = g[(size_t)row * 32 + cu];
                    v.x = pack_bf2(f.x, f.y);
                    v.y = pack_bf2(f.z, f.w);
                }
                *(uint2*)&xs[r * 68 + 2 * cu] = v;
            }
        }
        __syncthreads();
        const int w = t >> 6, lane = t & 63;
        const int l15 = lane & 15, quad = lane >> 4;
        const int a  = w & 3;      // out-col group (16 cols)
        const int g_ = w >> 2;     // node group (16 nodes)
        v4f acc = (v4f){0.f, 0.f, 0.f, 0.f};
#pragma unroll
        for (int k0 = 0; k0 < 128; k0 += 32) {
            const int ku = k0 / 2 + quad * 4;
            const v8s xb = *(const v8s*)&xs[(g_ * 16 + l15) * 68 + ku];
            const v8s wa = *(const v8s*)&ws[(16 * a + l15) * 68 + ku];
            acc = __builtin_amdgcn_mfma_f32_16x16x32_bf16(wa, xb, acc, 0, 0, 0);
        }
        // repack epilogue: stage fp32 tile in LDS, emit (d, d+32) bf16 pairs
        __syncthreads();
        float* stg = (float*)smem;                    // [64][68] fp32
        *(v4f*)&stg[(g_ * 16 + l15) * 68 + 16 * a + 4 * quad] = acc;
        __syncthreads();
        for (int i2 = t; i2 < 2048; i2 += 1024) {
            const int nl = i2 >> 5, d = i2 & 31;
            const int row = row0 + nl;
            if (row < N_NODES)
                hpre[(size_t)row * 32 + d] = pack_bf2(stg[nl * 68 + d], stg[nl * 68 + d + 32]);
        }
        return;
    }

    // ---- sort path: block-local counting sort of 4096 edges into 391 coarse buckets ----
    int*  hist  = smem;              // [391]
    int*  lcur  = smem + 391;        // [391]
    int*  tgb   = smem + 782;        // [391]
    int*  pairs = smem + 1173;       // [512] scan
    int*  tg    = smem + 1685;       // [4096]
    int2* ord   = (int2*)(smem + 5782); // [4096] (8B aligned)

    for (int i = t; i < NB_C; i += 1024) hist[i] = 0;
    __syncthreads();

    const int e0 = b * CHUNK_E;
    const int n = min(CHUNK_E, N_EDGES - e0);   // 4096, or 2560 for last block
    const int nI4 = n >> 2;
    const bool act = t < nI4;
    int4 sv, dv; float4 wv;
    if (act) {
        sv = ((const int4*)(src + e0))[t];
        dv = ((const int4*)(dst + e0))[t];
        wv = ((const float4*)(wgt + e0))[t];
        atomicAdd(&hist[dv.x >> 8], 1);
        atomicAdd(&hist[dv.y >> 8], 1);
        atomicAdd(&hist[dv.z >> 8], 1);
        atomicAdd(&hist[dv.w >> 8], 1);
    }
    __syncthreads();
    // Hillis-Steele inclusive scan over 512 (covers 391 bins)
    if (t < 512) pairs[t] = (t < NB_C) ? hist[t] : 0;
    __syncthreads();
    for (int off = 1; off < 512; off <<= 1) {
        int u = 0;
        if (t < 512 && t >= off) u = pairs[t - off];
        __syncthreads();
        if (t < 512) pairs[t] += u;
        __syncthreads();
    }
    if (t < NB_C) lcur[t] = pairs[t] - hist[t];     // exclusive
    __syncthreads();
    for (int i = t; i < NB_C; i += 1024) {
        const int hv = hist[i];
        const int lb = lcur[i];
        const int grsv = (hv > 0) ? atomicAdd(&gcount[i * GCSTRIDE], hv) : 0;
        tgb[i] = i * CAPC + grsv - lb;
    }
    __syncthreads();
    if (act) {
        {
            const int bk = dv.x >> 8;
            const int lp = atomicAdd(&lcur[bk], 1);
            ord[lp] = make_int2(sv.x | ((dv.x & 255) << 17), __float_as_int(wv.x));
            tg[lp] = tgb[bk] + lp;
        }
        {
            const int bk = dv.y >> 8;
            const int lp = atomicAdd(&lcur[bk], 1);
            ord[lp] = make_int2(sv.y | ((dv.y & 255) << 17), __float_as_int(wv.y));
            tg[lp] = tgb[bk] + lp;
        }
        {
            const int bk = dv.z >> 8;
            const int lp = atomicAdd(&lcur[bk], 1);
            ord[lp] = make_int2(sv.z | ((dv.z & 255) << 17), __float_as_int(wv.z));
            tg[lp] = tgb[bk] + lp;
        }
        {
            const int bk = dv.w >> 8;
            const int lp = atomicAdd(&lcur[bk], 1);
            ord[lp] = make_int2(sv.w | ((dv.w & 255) << 17), __float_as_int(wv.w));
            tg[lp] = tgb[bk] + lp;
        }
    }
    __syncthreads();
    // coalesced write-out: runs of ~10.5 records per bucket per chunk
    for (int i = t; i < n; i += 1024)
        arena[tg[i]] = ord[i];
}

// ---------- G: 32-node fine-bucket gather. Wave-aggregated compaction of the coarse
// bucket into an LDS queue, then 16-lane/record accumulation with native ds_add.
// FUSE=true adds in-block gemm2 (h1 @ W2), packed bf16 out; else fp32 out. ----------
template<bool FUSE>
__global__ __launch_bounds__(256) void gather_fuse(const unsigned* __restrict__ hsrc, // packed [N][32]
                                                   const int2* __restrict__ arena,
                                                   const int* __restrict__ gcount,
                                                   const float* __restrict__ bias,
                                                   const float* __restrict__ W2,
                                                   void* __restrict__ outp) {
    __shared__ int accs[32 * 68];            // acc [32][64] int; fp32 staging [32][68]
    __shared__ int2 qrec[QCAP];              // 6 KB compacted records
    __shared__ int qn_s;
    extern __shared__ unsigned wsdyn[];      // [64*36] bf16 W2^T (FUSE only)
    const int t = threadIdx.x;

    // bijective XCD swizzle (nwg=3125: q=390, r=5); keeps a coarse bucket's 8
    // sibling blocks contiguous on one XCD -> compaction re-reads are L2 hits.
    const int orig = blockIdx.x;
    const int xcd = orig & 7, idx = orig >> 3;
    const int b = (xcd < 5 ? xcd * 391 : 5 * 391 + (xcd - 5) * 390) + idx;

    const int cb = b >> 3;                   // coarse bucket (dst>>8)
    const int sub = b & 7;                   // fine eighth (dst>>5 & 7)
    for (int i = t; i < 2048; i += 256) accs[i] = 0;
    if (t == 0) qn_s = 0;
    if constexpr (FUSE) {
        const float2* g2 = (const float2*)W2;
        for (int i = t; i < 2048; i += 256) {
            const float2 v = g2[i];
            const int k = (2 * i) >> 6;
            const int c = (2 * i) & 63;
            ((short*)&wsdyn[c * 36])[k]       = (short)(pack_bf2(v.x, 0.f) & 0xFFFF);
            ((short*)&wsdyn[(c + 1) * 36])[k] = (short)(pack_bf2(v.y, 0.f) & 0xFFFF);
        }
    }
    __syncthreads();

    const int lane = t & 63;
    // compact my eighth's records: ballot + single atomic per wave (no same-address storm)
    {
        const int cntc = min(gcount[cb * GCSTRIDE], CAPC);
        const size_t cbase = (size_t)cb * CAPC;
        const unsigned long long below = (lane == 63) ? ~0ull >> 1
                                                      : (1ull << lane) - 1;
        for (int i = t; i < cntc; i += 256) {
            const int2 r = arena[cbase + i];
            const bool keep = ((r.x >> 22) & 7) == sub;
            const unsigned long long m = __ballot(keep);
            int base = 0;
            if (lane == 0) base = atomicAdd(&qn_s, __popcll(m));
            base = __builtin_amdgcn_readfirstlane(base);
            if (keep) {
                const int pos = base + __popcll(m & below);
                if (pos < QCAP) qrec[pos] = r;
            }
        }
    }
    __syncthreads();
    const int qn = min(qn_s, QCAP);
    const int npad = (qn + 63) & ~63;        // pad to mult of 64 with zero-weight recs
    for (int i = qn + t; i < npad; i += 256) qrec[i] = make_int2(0, 0);
    __syncthreads();

    // gather: 16 streams x 4-deep; lane loads uint2 at rotated dword-pair m
    const int li2 = t & 15;
    const int s   = t >> 4;                  // stream 0..15 (4 per wave)
    const int qw  = s & 3;
    const int m   = (li2 + 4 * qw) & 15;     // rotated pair index
    const int p   = qw & 1;                  // parity-order for bank spread
    for (int ib = s; ib < npad; ib += 64) {
        int2 r[4];
#pragma unroll
        for (int j = 0; j < 4; ++j) r[j] = qrec[ib + 16 * j];
        uint2 hv[4];
#pragma unroll
        for (int j = 0; j < 4; ++j)
            hv[j] = *(const uint2*)&hsrc[(size_t)(r[j].x & 0x1FFFF) * 32 + 2 * m];
#pragma unroll
        for (int j = 0; j < 4; ++j) {
            const int dl = (r[j].x >> 17) & 31;       // local node 0..31
            const float wsf = __int_as_float(r[j].y) * FIXSCALE;
            const float2 fa = bf2_to_f2(hv[j].x);     // cols (2m, 2m+32)
            const float2 fb = bf2_to_f2(hv[j].y);     // cols (2m+1, 2m+33)
            int* ap = &accs[dl * 64 + 2 * m];
            const float v0 = p ? fb.x : fa.x;         // col 2m+p
            const float v1 = p ? fa.x : fb.x;         // col 2m+1-p
            const float v2 = p ? fb.y : fa.y;         // col 2m+32+p
            const float v3 = p ? fa.y : fb.y;         // col 2m+33-p
            atomicAdd(ap + p,          (int)(wsf * v0));
            atomicAdd(ap + 1 - p,      (int)(wsf * v1));
            atomicAdd(ap + 32 + p,     (int)(wsf * v2));
            atomicAdd(ap + 33 - p,     (int)(wsf * v3));
        }
    }
    __syncthreads();

    if constexpr (FUSE) {
        // h1 = relu(acc*2^-20 + b1) -> bf16 (2c,2c+1) into xs[32][36] for MFMA K-order
        unsigned pk[4];
#pragma unroll
        for (int k = 0; k < 4; ++k) {
            const int i2 = t + k * 256;          // [0,1024): node=i2>>5, cp=i2&31
            const int node = i2 >> 5, cp = i2 & 31;
            const float f0 = fmaxf((float)accs[node * 64 + 2 * cp]     * FIXINV + bias[2 * cp],     0.f);
            const float f1 = fmaxf((float)accs[node * 64 + 2 * cp + 1] * FIXINV + bias[2 * cp + 1], 0.f);
            pk[k] = pack_bf2(f0, f1);
        }
        __syncthreads();
        unsigned* xs = (unsigned*)accs;          // overlay: [32][36]
#pragma unroll
        for (int k = 0; k < 4; ++k) {
            const int i2 = t + k * 256;
            xs[(i2 >> 5) * 36 + (i2 & 31)] = pk[k];
        }
        __syncthreads();
        // in-block gemm2 (M=32): wave w = col group; two node-group accumulators
        const int l15 = lane & 15, quad = lane >> 4;
        const int w = t >> 6;
        v4f a0 = (v4f){0.f, 0.f, 0.f, 0.f};
        v4f a1 = (v4f){0.f, 0.f, 0.f, 0.f};
#pragma unroll
        for (int k0 = 0; k0 < 64; k0 += 32) {
            const int ku = k0 / 2 + quad * 4;
            const v8s wa  = *(const v8s*)&wsdyn[(16 * w + l15) * 36 + ku];
            const v8s xb0 = *(const v8s*)&xs[l15 * 36 + ku];
            const v8s xb1 = *(const v8s*)&xs[(16 + l15) * 36 + ku];
            a0 = __builtin_amdgcn_mfma_f32_16x16x32_bf16(wa, xb0, a0, 0, 0, 0);
            a1 = __builtin_amdgcn_mfma_f32_16x16x32_bf16(wa, xb1, a1, 0, 0, 0);
        }
        __syncthreads();
        float* stg = (float*)accs;               // [32][68]
        *(v4f*)&stg[l15 * 68 + 16 * w + 4 * quad] = a0;
        *(v4f*)&stg[(16 + l15) * 68 + 16 * w + 4 * quad] = a1;
        __syncthreads();
        for (int i2 = t; i2 < 1024; i2 += 256) {
            const int nl = i2 >> 5, d = i2 & 31;
            const int ng = b * 32 + nl;          // NB_F*32 == N_NODES: no tail
            ((unsigned*)outp)[(size_t)ng * 32 + d] =
                pack_bf2(stg[nl * 68 + d], stg[nl * 68 + d + 32]);
        }
    } else {
        // out = relu(acc*2^-20 + b2), fp32
        for (int i2 = t; i2 < 1024; i2 += 256) {
            const int node = i2 >> 5, cp = i2 & 31;
            const int ng = b * 32 + node;
            float2 o;
            o.x = fmaxf((float)accs[node * 64 + 2 * cp]     * FIXINV + bias[2 * cp],     0.f);
            o.y = fmaxf((float)accs[node * 64 + 2 * cp + 1] * FIXINV + bias[2 * cp + 1], 0.f);
            *(float2*)&((float*)outp)[(size_t)ng * 64 + 2 * cp] = o;
        }
    }
}

extern "C" void kernel_launch(void* const* d_in, const int* in_sizes, int n_in,
                              void* d_out, int out_size, void* d_ws, size_t ws_size,
                              hipStream_t stream) {
    const float* x    = (const float*)d_in[0];          // [100000, 128]
    const int*   eidx = (const int*)d_in[1];            // [2, 1600000]
    const float* mask = (const float*)d_in[2];          // [1600000]
    const float* W1   = (const float*)d_in[3];          // [128, 64]
    const float* b1   = (const float*)d_in[4];          // [64]
    const float* W2   = (const float*)d_in[5];          // [64, 64]
    const float* b2   = (const float*)d_in[6];          // [64]
    float* out = (float*)d_out;                          // [100000, 64]

    const int* src = eidx;
    const int* dst = eidx + N_EDGES;

    // hpre (layer-1 pre-acts, packed bf16 [N][32] dwords = 12.8 MB) lives in d_out,
    // dead before G2 overwrites d_out with the final fp32 output.
    unsigned* hpre = (unsigned*)d_out;

    // workspace: coarse arena 14.4 MB | gcount 50 KB | hpre2 12.8 MB
    int2*     arena  = (int2*)d_ws;
    int*      gcount = (int*)(arena + (size_t)NB_C * CAPC);
    unsigned* hpre2  = (unsigned*)(gcount + NB_C * GCSTRIDE);

    const int gemmBlocks = (N_NODES + 63) / 64;          // 1563

    hipMemsetAsync(gcount, 0, NB_C * GCSTRIDE * sizeof(int), stream);

    // K1: coarse bucket scatter (blocks 0..390) + layer-1 GEMM tiles (blocks 391..1953)
    k1_sort_gemm<<<NBLK_S + gemmBlocks, 1024, 0, stream>>>(src, dst, mask, x, W1,
                                                           gcount, arena, hpre);

    // G1: gather layer 1 + fused gemm2 -> hpre2 (packed bf16)
    gather_fuse<true><<<NB_F, 256, 64 * 36 * 4, stream>>>(hpre, arena, gcount,
                                                          b1, W2, hpre2);
    // G2: gather layer 2 -> out (fp32)
    gather_fuse<false><<<NB_F, 256, 0, stream>>>(hpre2, arena, gcount,
                                                 b2, nullptr, out);
}

// Round 9
// 218.969 us; speedup vs baseline: 1.0371x; 1.0371x over previous
//
#include <hip/hip_runtime.h>
#include <hip/hip_bf16.h>

#define N_NODES 100000
#define N_EDGES 1600000
#define NB_C 391                    // coarse buckets (dst >> 8)
#define NB_F 1563                   // fine buckets (dst >> 6) = gather blocks
#define NBLK_S 391                  // sort chunks: ceil(1.6M / 4096)
#define CHUNK_E 4096                // one int4 (4 edges) per thread at 1024 threads
#define CAPC 4608                   // coarse arena capacity (mean 4092 + 8 sigma)
#define QCAP 1280                   // fine LDS queue cap (mean 1024 + 8 sigma), mult of 64
#define GCSTRIDE 32                 // one counter per 128B line
#define FIXSCALE 1048576.0f         // 2^20 fixed-point scale for LDS int accumulation
#define FIXINV   (1.0f / 1048576.0f)

// hpre/hpre2 packing: dword d of a row = bf16 pair (col d, col d+32).
// Gather: 16 lanes/record, lane loads uint2 (dwords 2m,2m+1, m rotated per stream);
// ds_adds parity-ordered so every atomic wave-instruction is exactly 2 lanes/bank.

typedef short v8s __attribute__((ext_vector_type(8)));
typedef float v4f __attribute__((ext_vector_type(4)));

static __device__ __forceinline__ unsigned pack_bf2(float a, float b) {
    __hip_bfloat162 p = __float22bfloat162_rn(make_float2(a, b));
    return *reinterpret_cast<unsigned*>(&p);
}
static __device__ __forceinline__ float2 bf2_to_f2(unsigned u) {
    __hip_bfloat162 p = *reinterpret_cast<__hip_bfloat162*>(&u);
    return __bfloat1622float2(p);
}

// ---------- K1 (1024 thr): blocks [0,NBLK_S) = coarse bucket scatter; rest = layer-1 GEMM ----------
__global__ __launch_bounds__(1024) void k1_sort_gemm(const int* __restrict__ src,
                                                     const int* __restrict__ dst,
                                                     const float* __restrict__ wgt,
                                                     const float* __restrict__ x,
                                                     const float* __restrict__ W1,
                                                     int* __restrict__ gcount,
                                                     int2* __restrict__ arena,
                                                     unsigned* __restrict__ hpre) {
    __shared__ __align__(16) int smem[13976];   // 55.9 KB union (sort view / gemm view)
    const int b = blockIdx.x;
    const int t = threadIdx.x;

    if (b >= NBLK_S) {
        // ---- layer-1 GEMM tile: hpre[64 nodes][32 dwords] = x_tile @ W1 (packed d,d+32) ----
        unsigned* xs = (unsigned*)smem;              // [64][68]
        unsigned* ws = (unsigned*)smem + 64 * 68;    // [64][68]
        const int tile = b - NBLK_S;
        const int row0 = tile * 64;
        {   // stage W1: fp32 [128][64] -> ws[col] bf16 at short index k (transpose)
            const float2* g2 = (const float2*)W1;
            for (int i = t; i < 64 * 128 / 2; i += 1024) {
                const float2 v = g2[i];
                const int k = (2 * i) >> 6;
                const int c = (2 * i) & 63;
                ((short*)&ws[c * 68])[k]       = (short)(pack_bf2(v.x, 0.f) & 0xFFFF);
                ((short*)&ws[(c + 1) * 68])[k] = (short)(pack_bf2(v.y, 0.f) & 0xFFFF);
            }
        }
        {   // stage x tile: fp32 -> bf16 packed
            const float4* g = (const float4*)x;
            for (int i = t; i < 64 * 32; i += 1024) {
                const int r = i >> 5, cu = i & 31;
                const int row = row0 + r;
                uint2 v = make_uint2(0u, 0u);
                if (row < N_NODES) {
                    float4 f = g[(size_t)row * 32 + cu];
                    v.x = pack_bf2(f.x, f.y);
                    v.y = pack_bf2(f.z, f.w);
                }
                *(uint2*)&xs[r * 68 + 2 * cu] = v;
            }
        }
        __syncthreads();
        const int w = t >> 6, lane = t & 63;
        const int l15 = lane & 15, quad = lane >> 4;
        const int a  = w & 3;      // out-col group (16 cols)
        const int g_ = w >> 2;     // node group (16 nodes)
        v4f acc = (v4f){0.f, 0.f, 0.f, 0.f};
#pragma unroll
        for (int k0 = 0; k0 < 128; k0 += 32) {
            const int ku = k0 / 2 + quad * 4;
            const v8s xb = *(const v8s*)&xs[(g_ * 16 + l15) * 68 + ku];
            const v8s wa = *(const v8s*)&ws[(16 * a + l15) * 68 + ku];
            acc = __builtin_amdgcn_mfma_f32_16x16x32_bf16(wa, xb, acc, 0, 0, 0);
        }
        // repack epilogue: stage fp32 tile in LDS, emit (d, d+32) bf16 pairs
        __syncthreads();
        float* stg = (float*)smem;                    // [64][68] fp32
        *(v4f*)&stg[(g_ * 16 + l15) * 68 + 16 * a + 4 * quad] = acc;
        __syncthreads();
        for (int i2 = t; i2 < 2048; i2 += 1024) {
            const int nl = i2 >> 5, d = i2 & 31;
            const int row = row0 + nl;
            if (row < N_NODES)
                hpre[(size_t)row * 32 + d] = pack_bf2(stg[nl * 68 + d], stg[nl * 68 + d + 32]);
        }
        return;
    }

    // ---- sort path: block-local counting sort of 4096 edges into 391 coarse buckets ----
    int*  hist  = smem;              // [391]
    int*  lcur  = smem + 391;        // [391]
    int*  tgb   = smem + 782;        // [391]
    int*  pairs = smem + 1173;       // [512] scan
    int*  tg    = smem + 1685;       // [4096]
    int2* ord   = (int2*)(smem + 5782); // [4096] (8B aligned)

    for (int i = t; i < NB_C; i += 1024) hist[i] = 0;
    __syncthreads();

    const int e0 = b * CHUNK_E;
    const int n = min(CHUNK_E, N_EDGES - e0);   // 4096, or 2560 for last block
    const int nI4 = n >> 2;
    const bool act = t < nI4;
    int4 sv, dv; float4 wv;
    if (act) {
        sv = ((const int4*)(src + e0))[t];
        dv = ((const int4*)(dst + e0))[t];
        wv = ((const float4*)(wgt + e0))[t];
        atomicAdd(&hist[dv.x >> 8], 1);
        atomicAdd(&hist[dv.y >> 8], 1);
        atomicAdd(&hist[dv.z >> 8], 1);
        atomicAdd(&hist[dv.w >> 8], 1);
    }
    __syncthreads();
    // Hillis-Steele inclusive scan over 512 (covers 391 bins)
    if (t < 512) pairs[t] = (t < NB_C) ? hist[t] : 0;
    __syncthreads();
    for (int off = 1; off < 512; off <<= 1) {
        int u = 0;
        if (t < 512 && t >= off) u = pairs[t - off];
        __syncthreads();
        if (t < 512) pairs[t] += u;
        __syncthreads();
    }
    if (t < NB_C) lcur[t] = pairs[t] - hist[t];     // exclusive
    __syncthreads();
    for (int i = t; i < NB_C; i += 1024) {
        const int hv = hist[i];
        const int lb = lcur[i];
        const int grsv = (hv > 0) ? atomicAdd(&gcount[i * GCSTRIDE], hv) : 0;
        tgb[i] = i * CAPC + grsv - lb;
    }
    __syncthreads();
    if (act) {
        {
            const int bk = dv.x >> 8;
            const int lp = atomicAdd(&lcur[bk], 1);
            ord[lp] = make_int2(sv.x | ((dv.x & 255) << 17), __float_as_int(wv.x));
            tg[lp] = tgb[bk] + lp;
        }
        {
            const int bk = dv.y >> 8;
            const int lp = atomicAdd(&lcur[bk], 1);
            ord[lp] = make_int2(sv.y | ((dv.y & 255) << 17), __float_as_int(wv.y));
            tg[lp] = tgb[bk] + lp;
        }
        {
            const int bk = dv.z >> 8;
            const int lp = atomicAdd(&lcur[bk], 1);
            ord[lp] = make_int2(sv.z | ((dv.z & 255) << 17), __float_as_int(wv.z));
            tg[lp] = tgb[bk] + lp;
        }
        {
            const int bk = dv.w >> 8;
            const int lp = atomicAdd(&lcur[bk], 1);
            ord[lp] = make_int2(sv.w | ((dv.w & 255) << 17), __float_as_int(wv.w));
            tg[lp] = tgb[bk] + lp;
        }
    }
    __syncthreads();
    // coalesced write-out: runs of ~10.5 records per bucket per chunk
    for (int i = t; i < n; i += 1024)
        arena[tg[i]] = ord[i];
}

// ---------- G: 64-node fine-bucket gather. Ballot-aggregated compaction of the coarse
// bucket quarter into an LDS queue, then 16-lane/record accumulation, native ds_add.
// FUSE=true adds in-block gemm2 (h1 @ W2), packed bf16 out; else fp32 out. ----------
template<bool FUSE>
__global__ __launch_bounds__(256) void gather_fuse(const unsigned* __restrict__ hsrc, // packed [N][32]
                                                   const int2* __restrict__ arena,
                                                   const int* __restrict__ gcount,
                                                   const float* __restrict__ bias,
                                                   const float* __restrict__ W2,
                                                   void* __restrict__ outp) {
    __shared__ int accs[64 * 68];            // acc [64][64] int; fp32 staging [64][68]
    __shared__ int2 qrec[QCAP];              // 10.2 KB compacted records
    __shared__ int qn_s;
    extern __shared__ unsigned wsdyn[];      // [64*36] bf16 W2^T (FUSE only)
    const int t = threadIdx.x;

    // bijective XCD swizzle (nwg=1563: q=195, r=3): a coarse bucket's 4 sibling
    // blocks stay contiguous on one XCD -> compaction re-reads are L2 hits.
    const int orig = blockIdx.x;
    const int xcd = orig & 7, idx = orig >> 3;
    const int b = (xcd < 3 ? xcd * 196 : 3 * 196 + (xcd - 3) * 195) + idx;

    const int cb = b >> 2;                   // coarse bucket (dst>>8)
    const int sub = b & 3;                   // fine quarter (dst>>6 & 3) = rec bits 23-24
    for (int i = t; i < 4096; i += 256) accs[i] = 0;
    if (t == 0) qn_s = 0;
    if constexpr (FUSE) {
        const float2* g2 = (const float2*)W2;
        for (int i = t; i < 2048; i += 256) {
            const float2 v = g2[i];
            const int k = (2 * i) >> 6;
            const int c = (2 * i) & 63;
            ((short*)&wsdyn[c * 36])[k]       = (short)(pack_bf2(v.x, 0.f) & 0xFFFF);
            ((short*)&wsdyn[(c + 1) * 36])[k] = (short)(pack_bf2(v.y, 0.f) & 0xFFFF);
        }
    }
    __syncthreads();

    const int lane = t & 63;
    // compact: uniform-bound int4 reads (2 records/lane) + ballot-aggregated append
    {
        const int cntc = min(gcount[cb * GCSTRIDE], CAPC);
        const size_t cbase = (size_t)cb * CAPC;
        const int4* a4p = (const int4*)(arena + cbase);
        const int np = cntc >> 1;
        const unsigned long long below = (lane == 63) ? (~0ull >> 1)
                                                      : ((1ull << lane) - 1);
        for (int i0 = 0; i0 < np; i0 += 256) {       // uniform bound: lane 0 always active
            const int i = i0 + t;
            int4 pr = make_int4(0, 0, 0, 0);
            if (i < np) pr = a4p[i];
            const bool k0 = (i < np) && (((pr.x >> 23) & 3) == sub);
            const bool k1 = (i < np) && (((pr.z >> 23) & 3) == sub);
            const unsigned long long m0 = __ballot(k0);
            const unsigned long long m1 = __ballot(k1);
            int base = 0;
            if (lane == 0) base = atomicAdd(&qn_s, __popcll(m0) + __popcll(m1));
            base = __builtin_amdgcn_readfirstlane(base);
            if (k0) {
                const int pos = base + __popcll(m0 & below);
                if (pos < QCAP) qrec[pos] = make_int2(pr.x, pr.y);
            }
            if (k1) {
                const int pos = base + __popcll(m0) + __popcll(m1 & below);
                if (pos < QCAP) qrec[pos] = make_int2(pr.z, pr.w);
            }
        }
        if ((cntc & 1) && t == 0) {                  // odd tail record
            const int2 r = arena[cbase + cntc - 1];
            if (((r.x >> 23) & 3) == sub) {
                const int pos = atomicAdd(&qn_s, 1);
                if (pos < QCAP) qrec[pos] = r;
            }
        }
    }
    __syncthreads();
    const int qn = min(qn_s, QCAP);
    const int npad = (qn + 63) & ~63;        // pad to mult of 64 with zero-weight recs
    for (int i = qn + t; i < npad; i += 256) qrec[i] = make_int2(0, 0);
    __syncthreads();

    // gather: 16 streams x 4-deep; lane loads uint2 at rotated dword-pair m
    const int li2 = t & 15;
    const int s   = t >> 4;                  // stream 0..15 (4 per wave)
    const int qw  = s & 3;
    const int m   = (li2 + 4 * qw) & 15;     // rotated pair index
    const int p   = qw & 1;                  // parity-order for bank spread
    for (int ib = s; ib < npad; ib += 64) {
        int2 r[4];
#pragma unroll
        for (int j = 0; j < 4; ++j) r[j] = qrec[ib + 16 * j];
        uint2 hv[4];
#pragma unroll
        for (int j = 0; j < 4; ++j)
            hv[j] = *(const uint2*)&hsrc[(size_t)(r[j].x & 0x1FFFF) * 32 + 2 * m];
#pragma unroll
        for (int j = 0; j < 4; ++j) {
            const int dl = (r[j].x >> 17) & 63;       // local node 0..63
            const float wsf = __int_as_float(r[j].y) * FIXSCALE;
            const float2 fa = bf2_to_f2(hv[j].x);     // cols (2m, 2m+32)
            const float2 fb = bf2_to_f2(hv[j].y);     // cols (2m+1, 2m+33)
            int* ap = &accs[dl * 64 + 2 * m];
            const float v0 = p ? fb.x : fa.x;         // col 2m+p
            const float v1 = p ? fa.x : fb.x;         // col 2m+1-p
            const float v2 = p ? fb.y : fa.y;         // col 2m+32+p
            const float v3 = p ? fa.y : fb.y;         // col 2m+33-p
            atomicAdd(ap + p,          (int)(wsf * v0));
            atomicAdd(ap + 1 - p,      (int)(wsf * v1));
            atomicAdd(ap + 32 + p,     (int)(wsf * v2));
            atomicAdd(ap + 33 - p,     (int)(wsf * v3));
        }
    }
    __syncthreads();

    if constexpr (FUSE) {
        // h1 = relu(acc*2^-20 + b1) -> bf16 (2c,2c+1) into xs[64][36] for MFMA K-order
        unsigned pk[8];
#pragma unroll
        for (int k = 0; k < 8; ++k) {
            const int i2 = t + k * 256;          // [0,2048): node=i2>>5, cp=i2&31
            const int node = i2 >> 5, cp = i2 & 31;
            const float f0 = fmaxf((float)accs[node * 64 + 2 * cp]     * FIXINV + bias[2 * cp],     0.f);
            const float f1 = fmaxf((float)accs[node * 64 + 2 * cp + 1] * FIXINV + bias[2 * cp + 1], 0.f);
            pk[k] = pack_bf2(f0, f1);
        }
        __syncthreads();
        unsigned* xs = (unsigned*)accs;          // overlay: [64][36]
#pragma unroll
        for (int k = 0; k < 8; ++k) {
            const int i2 = t + k * 256;
            xs[(i2 >> 5) * 36 + (i2 & 31)] = pk[k];
        }
        __syncthreads();
        // in-block gemm2: hpre2[64][32 dwords] = h1_tile @ W2, packed (d, d+32)
        const int w = t >> 6, l15 = lane & 15, quad = lane >> 4;
        v4f a4[4];
#pragma unroll
        for (int tt = 0; tt < 4; ++tt) a4[tt] = (v4f){0.f, 0.f, 0.f, 0.f};
#pragma unroll
        for (int k0 = 0; k0 < 64; k0 += 32) {
            const int ku = k0 / 2 + quad * 4;
            const v8s xb = *(const v8s*)&xs[(w * 16 + l15) * 36 + ku];
#pragma unroll
            for (int tt = 0; tt < 4; ++tt) {
                const v8s wa = *(const v8s*)&wsdyn[(16 * tt + l15) * 36 + ku];
                a4[tt] = __builtin_amdgcn_mfma_f32_16x16x32_bf16(wa, xb, a4[tt], 0, 0, 0);
            }
        }
        __syncthreads();
        float* stg = (float*)accs;               // [64][68]
#pragma unroll
        for (int tt = 0; tt < 4; ++tt)
            *(v4f*)&stg[(w * 16 + l15) * 68 + 16 * tt + 4 * quad] = a4[tt];
        __syncthreads();
        for (int i2 = t; i2 < 2048; i2 += 256) {
            const int nl = i2 >> 5, d = i2 & 31;
            const int ng = b * 64 + nl;
            if (ng < N_NODES)
                ((unsigned*)outp)[(size_t)ng * 32 + d] =
                    pack_bf2(stg[nl * 68 + d], stg[nl * 68 + d + 32]);
        }
    } else {
        // out = relu(acc*2^-20 + b2), fp32
        for (int i2 = t; i2 < 2048; i2 += 256) {
            const int node = i2 >> 5, cp = i2 & 31;
            const int ng = b * 64 + node;
            if (ng < N_NODES) {
                float2 o;
                o.x = fmaxf((float)accs[node * 64 + 2 * cp]     * FIXINV + bias[2 * cp],     0.f);
                o.y = fmaxf((float)accs[node * 64 + 2 * cp + 1] * FIXINV + bias[2 * cp + 1], 0.f);
                *(float2*)&((float*)outp)[(size_t)ng * 64 + 2 * cp] = o;
            }
        }
    }
}

extern "C" void kernel_launch(void* const* d_in, const int* in_sizes, int n_in,
                              void* d_out, int out_size, void* d_ws, size_t ws_size,
                              hipStream_t stream) {
    const float* x    = (const float*)d_in[0];          // [100000, 128]
    const int*   eidx = (const int*)d_in[1];            // [2, 1600000]
    const float* mask = (const float*)d_in[2];          // [1600000]
    const float* W1   = (const float*)d_in[3];          // [128, 64]
    const float* b1   = (const float*)d_in[4];          // [64]
    const float* W2   = (const float*)d_in[5];          // [64, 64]
    const float* b2   = (const float*)d_in[6];          // [64]
    float* out = (float*)d_out;                          // [100000, 64]

    const int* src = eidx;
    const int* dst = eidx + N_EDGES;

    // hpre (layer-1 pre-acts, packed bf16 [N][32] dwords = 12.8 MB) lives in d_out,
    // dead before G2 overwrites d_out with the final fp32 output.
    unsigned* hpre = (unsigned*)d_out;

    // workspace: coarse arena 14.4 MB | gcount 50 KB | hpre2 12.8 MB
    int2*     arena  = (int2*)d_ws;
    int*      gcount = (int*)(arena + (size_t)NB_C * CAPC);
    unsigned* hpre2  = (unsigned*)(gcount + NB_C * GCSTRIDE);

    const int gemmBlocks = (N_NODES + 63) / 64;          // 1563

    hipMemsetAsync(gcount, 0, NB_C * GCSTRIDE * sizeof(int), stream);

    // K1: coarse bucket scatter (blocks 0..390) + layer-1 GEMM tiles (blocks 391..1953)
    k1_sort_gemm<<<NBLK_S + gemmBlocks, 1024, 0, stream>>>(src, dst, mask, x, W1,
                                                           gcount, arena, hpre);

    // G1: gather layer 1 + fused gemm2 -> hpre2 (packed bf16)
    gather_fuse<true><<<NB_F, 256, 64 * 36 * 4, stream>>>(hpre, arena, gcount,
                                                          b1, W2, hpre2);
    // G2: gather layer 2 -> out (fp32)
    gather_fuse<false><<<NB_F, 256, 0, stream>>>(hpre2, arena, gcount,
                                                 b2, nullptr, out);
}